// Round 3
// baseline (60.526 us; speedup 1.0000x reference)
//
#include <hip/hip_runtime.h>

// similarity[r] = sum_a (pp[r,a] - ph[a])^2, a in [0,32); output = min_r similarity[r]
// pp: [R, 32] fp32 row-major, ph: [32] fp32, out: 1 fp32 scalar.
//
// Round-3 structure: coalesced global loads + LDS transpose stage.
//  - 8 independent coalesced float4 loads per thread (1 KB/wave-instr, 8 KB
//    in flight per wave -> covers HBM latency).
//  - LDS laid out as float4 [256][9]: +1-float4 pad rotates banks per row, so
//    both the coalesced ds_write_b128 and the per-row ds_read_b128 are
//    conflict-free (each 8-lane run covers all 32 banks exactly once).
//  - Each lane then computes its own row's distance locally: zero shuffles in
//    the data path; one min butterfly + one atomicMin per block.

__global__ void doa_init_out(unsigned int* out) {
    // +inf bits; fp32 sums of squares are >= 0, so uint ordering == float ordering
    *out = 0x7F800000u;
}

__global__ __launch_bounds__(256) void doa_min_kernel(
    const float* __restrict__ pp,
    const float* __restrict__ ph,
    unsigned int* __restrict__ out,
    int R)
{
    __shared__ float4 lds[256 * 9];   // 36 KB: 256 rows x (8 data + 1 pad) float4

    const int t = threadIdx.x;
    const long long base_row = (long long)blockIdx.x * 256;

    // phases: wave-uniform -> SGPRs
    float q[32];
#pragma unroll
    for (int a = 0; a < 32; ++a) q[a] = ph[a];

    // Stage 1: 8 independent coalesced float4 loads per thread.
    const float4* src = reinterpret_cast<const float4*>(pp);
    const long long gmax = (long long)R * 8;
    float4 v[8];
#pragma unroll
    for (int i = 0; i < 8; ++i) {
        long long g = base_row * 8 + i * 256 + t;
        if (g >= gmax) g = 0;          // clamp; value unused for r >= R
        v[i] = src[g];
    }
#pragma unroll
    for (int i = 0; i < 8; ++i) {
        const int idx = i * 256 + t;   // float4 index within block's 256 rows
        const int row = idx >> 3;
        const int k   = idx & 7;
        lds[row * 9 + k] = v[i];       // padded row stride -> conflict-free
    }
    __syncthreads();

    // Stage 2: each lane computes its own row entirely from LDS.
    float s = __builtin_inff();
    if (base_row + t < R) {
        s = 0.0f;
#pragma unroll
        for (int k = 0; k < 8; ++k) {
            const float4 p = lds[t * 9 + k];
            const float dx = p.x - q[4 * k + 0];
            const float dy = p.y - q[4 * k + 1];
            const float dz = p.z - q[4 * k + 2];
            const float dw = p.w - q[4 * k + 3];
            s += dx * dx + dy * dy + dz * dz + dw * dw;
        }
    }

    // One wave-wide min butterfly per wave lifetime
#pragma unroll
    for (int off = 1; off < 64; off <<= 1)
        s = fminf(s, __shfl_xor(s, off));

    __shared__ float wmin[4];
    const int lane = t & 63;
    const int wid  = t >> 6;
    if (lane == 0) wmin[wid] = s;
    __syncthreads();
    if (t == 0) {
        const float m = fminf(fminf(wmin[0], wmin[1]), fminf(wmin[2], wmin[3]));
        atomicMin(out, __float_as_uint(m));
    }
}

extern "C" void kernel_launch(void* const* d_in, const int* in_sizes, int n_in,
                              void* d_out, int out_size, void* d_ws, size_t ws_size,
                              hipStream_t stream) {
    const float* pp = (const float*)d_in[0];   // possible_phases [R, 32]
    const float* ph = (const float*)d_in[1];   // phases [32]
    unsigned int* out = (unsigned int*)d_out;  // 1 fp32 scalar

    const int R = in_sizes[0] / 32;

    doa_init_out<<<1, 1, 0, stream>>>(out);

    const int block = 256;
    const int grid = (R + 255) / 256;          // one 256-row stage per block
    doa_min_kernel<<<grid, block, 0, stream>>>(pp, ph, out, R);
}

// Round 4
// 26.449 us; speedup vs baseline: 2.2884x; 2.2884x over previous
//
#include <hip/hip_runtime.h>

// similarity[r] = sum_a (pp[r,a] - ph[a])^2, a in [0,32); output = min_r similarity[r]
// pp: [R, 32] fp32 row-major, ph: [32] fp32, out: 1 fp32 scalar.
//
// Round-4: same coalesced + LDS-transpose stage as round 3, but NO global
// atomics. Rounds 2 & 3 had identical 60 us despite opposite memory patterns
// -> bound by 3907 same-address device atomicMins (~6 ns each, cacheline
// bouncing across 8 XCDs). Each block now plain-stores its partial min to
// d_ws[blockIdx.x]; a tiny second kernel reduces the partials.

__global__ __launch_bounds__(256) void doa_stage_kernel(
    const float* __restrict__ pp,
    const float* __restrict__ ph,
    float* __restrict__ ws,
    int R)
{
    __shared__ float4 lds[256 * 9];   // 36 KB: 256 rows x (8 data + 1 pad) float4

    const int t = threadIdx.x;
    const long long base_row = (long long)blockIdx.x * 256;

    // phases: wave-uniform -> SGPRs
    float q[32];
#pragma unroll
    for (int a = 0; a < 32; ++a) q[a] = ph[a];

    // Stage 1: 8 independent coalesced float4 loads per thread (8 KB/wave in flight)
    const float4* src = reinterpret_cast<const float4*>(pp);
    const long long gmax = (long long)R * 8;
    float4 v[8];
#pragma unroll
    for (int i = 0; i < 8; ++i) {
        long long g = base_row * 8 + i * 256 + t;
        if (g >= gmax) g = 0;          // clamp; value unused for r >= R
        v[i] = src[g];
    }
#pragma unroll
    for (int i = 0; i < 8; ++i) {
        const int idx = i * 256 + t;   // float4 index within block's 256 rows
        lds[(idx >> 3) * 9 + (idx & 7)] = v[i];   // padded stride: conflict-free
    }
    __syncthreads();

    // Stage 2: each lane computes its own row from LDS (no shuffles in data path)
    float s = __builtin_inff();
    if (base_row + t < R) {
        s = 0.0f;
#pragma unroll
        for (int k = 0; k < 8; ++k) {
            const float4 p = lds[t * 9 + k];
            const float dx = p.x - q[4 * k + 0];
            const float dy = p.y - q[4 * k + 1];
            const float dz = p.z - q[4 * k + 2];
            const float dw = p.w - q[4 * k + 3];
            s += dx * dx + dy * dy + dz * dz + dw * dw;
        }
    }

#pragma unroll
    for (int off = 1; off < 64; off <<= 1)
        s = fminf(s, __shfl_xor(s, off));

    __shared__ float wmin[4];
    const int lane = t & 63;
    const int wid  = t >> 6;
    if (lane == 0) wmin[wid] = s;
    __syncthreads();
    if (t == 0) {
        // plain store, no contention
        ws[blockIdx.x] = fminf(fminf(wmin[0], wmin[1]), fminf(wmin[2], wmin[3]));
    }
}

__global__ __launch_bounds__(1024) void doa_reduce_kernel(
    const float* __restrict__ ws,
    float* __restrict__ out,
    int n)
{
    float s = __builtin_inff();
    for (int i = threadIdx.x; i < n; i += 1024)
        s = fminf(s, ws[i]);

#pragma unroll
    for (int off = 1; off < 64; off <<= 1)
        s = fminf(s, __shfl_xor(s, off));

    __shared__ float wmin[16];
    if ((threadIdx.x & 63) == 0) wmin[threadIdx.x >> 6] = s;
    __syncthreads();
    if (threadIdx.x == 0) {
        float m = wmin[0];
#pragma unroll
        for (int w = 1; w < 16; ++w) m = fminf(m, wmin[w]);
        *out = m;   // unconditional write every call: deterministic, no init kernel
    }
}

extern "C" void kernel_launch(void* const* d_in, const int* in_sizes, int n_in,
                              void* d_out, int out_size, void* d_ws, size_t ws_size,
                              hipStream_t stream) {
    const float* pp = (const float*)d_in[0];   // possible_phases [R, 32]
    const float* ph = (const float*)d_in[1];   // phases [32]
    float* out = (float*)d_out;                // 1 fp32 scalar
    float* ws  = (float*)d_ws;                 // per-block partial mins

    const int R = in_sizes[0] / 32;
    const int grid = (R + 255) / 256;          // 3907 blocks for R = 1e6

    doa_stage_kernel<<<grid, 256, 0, stream>>>(pp, ph, ws, R);
    doa_reduce_kernel<<<1, 1024, 0, stream>>>(ws, out, grid);
}